// Round 7
// baseline (409.476 us; speedup 1.0000x reference)
//
#include <hip/hip_runtime.h>
#include <hip/hip_cooperative_groups.h>
#include <math.h>

namespace cg = cooperative_groups;

#define NN 4096
#define DD 256
#define KK 2048
#define NW 64   // u64 words per bitmask row

// Build sorted column list for bitmask row r into LDS `cols` (one wave, lane l).
// Returns total bit count. List is ascending.
__device__ __forceinline__ int build_list(const unsigned long long* __restrict__ B, int r,
                                          int l, int* cols, int cap) {
    unsigned long long word = B[(size_t)r * NW + l];
    int pc = __popcll(word);
    int off = pc;
    for (int d = 1; d < 64; d <<= 1) {
        int n = __shfl_up(off, d);
        if (l >= d) off += n;
    }
    int total = __shfl(off, 63);
    int base = off - pc;
    while (word) {
        int b = (int)__ffsll(word) - 1;
        word &= word - 1;
        if (base < cap) cols[base] = l * 64 + b;
        ++base;
    }
    return total;
}

// ---------------- fused: column stats partials (blocks 0..63) + g bitmask (blocks 64..4159) ----
__global__ void k_pre(const float* __restrict__ h, const float* __restrict__ g,
                      double* __restrict__ psum, double* __restrict__ psq,
                      unsigned long long* __restrict__ B) {
    int blk = blockIdx.x;
    int t = threadIdx.x;   // 256
    if (blk < 64) {
        int d = t;
        int r0 = blk * 64;
        double s0=0,s1=0,s2=0,s3=0,q0=0,q1=0,q2=0,q3=0;
        for (int k = 0; k < 64; k += 4) {
            double x0 = (double)h[(size_t)(r0+k+0) * DD + d];
            double x1 = (double)h[(size_t)(r0+k+1) * DD + d];
            double x2 = (double)h[(size_t)(r0+k+2) * DD + d];
            double x3 = (double)h[(size_t)(r0+k+3) * DD + d];
            s0 += x0; q0 += x0*x0;
            s1 += x1; q1 += x1*x1;
            s2 += x2; q2 += x2*x2;
            s3 += x3; q3 += x3*x3;
        }
        psum[blk * DD + d] = (s0+s1)+(s2+s3);
        psq [blk * DD + d] = (q0+q1)+(q2+q3);
    } else {
        int i = blk - 64;
        int q = t >> 6, l = t & 63;
        const float4* g4 = (const float4*)(g + (size_t)i * NN);
        for (int wi = 0; wi < 4; ++wi) {
            float4 v = g4[q * 256 + wi * 64 + l];
            unsigned int nib = (unsigned int)(v.x != 0.f)
                             | ((unsigned int)(v.y != 0.f) << 1)
                             | ((unsigned int)(v.z != 0.f) << 2)
                             | ((unsigned int)(v.w != 0.f) << 3);
            unsigned long long word = (unsigned long long)nib << (4 * (l & 15));
            unsigned int lo = (unsigned int)word, hi = (unsigned int)(word >> 32);
            for (int s = 1; s < 16; s <<= 1) {
                lo |= __shfl_xor(lo, s, 16);
                hi |= __shfl_xor(hi, s, 16);
            }
            if ((l & 15) == 0)
                B[(size_t)i * NW + 16 * q + 4 * wi + (l >> 4)] =
                    ((unsigned long long)hi << 32) | lo;
        }
    }
}

// ---------------- mega cooperative kernel: everything after k_pre, 512 blocks x 256 ----------
__global__ __launch_bounds__(256, 2) void k_coop(
    const float* __restrict__ h, const float* __restrict__ gamma,
    const float* __restrict__ beta, const float* __restrict__ w,
    const float* __restrict__ bp, const float* __restrict__ sigma1,
    const double* __restrict__ psum, const double* __restrict__ psq,
    const unsigned long long* __restrict__ B,
    double* __restrict__ mu, double* __restrict__ rstd,
    float* __restrict__ hn, double* __restrict__ zpf,
    unsigned long long* __restrict__ T, double* __restrict__ Z1,
    double* __restrict__ Z3, int* __restrict__ degi,
    float* __restrict__ scores, int* __restrict__ idx_int,
    float* __restrict__ inv_rs, float* __restrict__ out_gnew,
    float* __restrict__ out_newh, float* __restrict__ out_idx)
{
    cg::grid_group grid = cg::this_grid();
    __shared__ union U {
        unsigned long long Kl[NN];     // rank phase: all sort keys (32 KB)
        int cols4[4][2048];            // list phases: per-wave column lists
        unsigned long long Sl[NW];     // rowsum phase: selected-set bitmap
    } sh;
    __shared__ double red[256];
    __shared__ unsigned long long Tl4[4][NW];
    const int blk = blockIdx.x;        // 0..511
    const int t = threadIdx.x;         // 0..255
    const int wv = t >> 6, l = t & 63;
    const int gw = blk * 4 + wv;       // global wave id 0..2047

    // ======== P0: column-stats final (blocks 0..63, wave per dim) ========
    if (blk < 64) {
        int d = blk * 4 + wv;
        double s = psum[l * DD + d];
        double q = psq [l * DD + d];
        for (int off = 32; off > 0; off >>= 1) {
            s += __shfl_down(s, off);
            q += __shfl_down(q, off);
        }
        if (l == 0) {
            double m = s / (double)NN;
            double var = q / (double)NN - m * m;
            mu[d]   = m;
            rstd[d] = 1.0 / sqrt(var + 1e-5);
        }
    }
    grid.sync();

    // ======== P1: twohop (2 rows/wave) then agg+norm+zpf (2 rows/wave) ========
    {
        int* cols = sh.cols4[wv];
        for (int pass = 0; pass < 2; ++pass) {
            int r = gw + pass * 2048;
            int cnt = build_list(B, r, l, cols, 128);
            if (cnt > 128) cnt = 128;
            unsigned long long a0 = 0ull, a1 = 0ull;
            int j = 0;
            for (; j + 1 < cnt; j += 2) {
                a0 |= B[(size_t)cols[j]     * NW + l];
                a1 |= B[(size_t)cols[j + 1] * NW + l];
            }
            if (j < cnt) a0 |= B[(size_t)cols[j] * NW + l];
            T[(size_t)r * NW + l] = a0 | a1;
        }
        const float4*  h4  = (const float4*)h;
        const double2* mu2 = (const double2*)mu;
        const double2* rs2 = (const double2*)rstd;
        const float4*  ga4 = (const float4*)gamma;
        const float4*  be4 = (const float4*)beta;
        const float4*  w4  = (const float4*)w;
        double2 mA = mu2[2*l], mB = mu2[2*l+1];
        double2 rA = rs2[2*l], rB = rs2[2*l+1];
        float4 ga = ga4[l], be = be4[l], wl = w4[l];
        for (int pass = 0; pass < 2; ++pass) {
            int r = gw + pass * 2048;
            int cnt = build_list(B, r, l, cols, 128);
            if (cnt > 128) cnt = 128;
            double s0=0,s1=0,s2=0,s3=0,u0=0,u1=0,u2=0,u3=0;
            int j = 0;
            for (; j + 1 < cnt; j += 2) {
                float4 v0 = h4[(size_t)cols[j]     * 64 + l];
                float4 v1 = h4[(size_t)cols[j + 1] * 64 + l];
                s0 += (double)v0.x; s1 += (double)v0.y; s2 += (double)v0.z; s3 += (double)v0.w;
                u0 += (double)v1.x; u1 += (double)v1.y; u2 += (double)v1.z; u3 += (double)v1.w;
            }
            if (j < cnt) {
                float4 v0 = h4[(size_t)cols[j] * 64 + l];
                s0 += (double)v0.x; s1 += (double)v0.y; s2 += (double)v0.z; s3 += (double)v0.w;
            }
            s0 += u0; s1 += u1; s2 += u2; s3 += u3;
            double inv = 1.0 / (double)cnt;
            double g0 = (s0 * inv - mA.x) * rA.x * (double)ga.x + (double)be.x;
            double g1 = (s1 * inv - mA.y) * rA.y * (double)ga.y + (double)be.y;
            double g2 = (s2 * inv - mB.x) * rB.x * (double)ga.z + (double)be.z;
            double g3 = (s3 * inv - mB.y) * rB.y * (double)ga.w + (double)be.w;
            float4 hv = h4[(size_t)r * 64 + l];
            double h0 = ((double)hv.x - mA.x) * rA.x * (double)ga.x + (double)be.x;
            double h1 = ((double)hv.y - mA.y) * rA.y * (double)ga.y + (double)be.y;
            double h2 = ((double)hv.z - mB.x) * rB.x * (double)ga.z + (double)be.z;
            double h3 = ((double)hv.w - mB.y) * rB.y * (double)ga.w + (double)be.w;
            float4 o = { (float)h0, (float)h1, (float)h2, (float)h3 };
            ((float4*)hn)[(size_t)r * 64 + l] = o;
            double z1p = (fabs(h0 - g0) + fabs(h1 - g1)) + (fabs(h2 - g2) + fabs(h3 - g3));
            double z3p = (g0 * (double)wl.x + g1 * (double)wl.y)
                       + (g2 * (double)wl.z + g3 * (double)wl.w);
            double zfp = (h0 * (double)wl.x + h1 * (double)wl.y)
                       + (h2 * (double)wl.z + h3 * (double)wl.w);
            for (int off = 32; off > 0; off >>= 1) {
                z1p += __shfl_down(z1p, off);
                z3p += __shfl_down(z3p, off);
                zfp += __shfl_down(zfp, off);
            }
            if (l == 0) {
                Z1[r] = z1p;
                Z3[r] = z3p + (double)bp[0];
                zpf[r] = zfp + (double)bp[0];
                degi[r] = cnt;
            }
        }
    }
    grid.sync();

    // ======== P2: redundant deterministic softmax + all keys in LDS + rank 8 i's ========
    {
        double mx = -1e300;
        for (int k = 0; k < 16; ++k) mx = fmax(mx, Z3[t + 256 * k]);
        red[t] = mx;
        __syncthreads();
        for (int s = 128; s > 0; s >>= 1) {
            if (t < s) red[t] = fmax(red[t], red[t + s]);
            __syncthreads();
        }
        double M = red[0];
        __syncthreads();
        double se = 0.0;
        for (int k = 0; k < 16; ++k) se += exp(Z3[t + 256 * k] - M);
        red[t] = se;
        __syncthreads();
        for (int s = 128; s > 0; s >>= 1) {
            if (t < s) red[t] += red[t + s];
            __syncthreads();
        }
        double sum = red[0];
        double s1 = (double)sigma1[0];
        for (int k = 0; k < 16; ++k) {
            int i = t + 256 * k;
            double pg = exp(Z3[i] - M) / sum;
            double pl = 1.0 / (1.0 + exp(-(Z1[i] + (double)degi[i])));
            double pt = 1.0 / (1.0 + exp(-(pl + pg)));
            double pf = 1.0 / (1.0 + exp(-zpf[i]));
            float sc = (float)(s1 * pt + (1.0 - s1) * pf);
            if ((i >> 3) == blk) scores[i] = sc;   // unique writer per i
            unsigned int b2 = __float_as_uint(sc);
            unsigned int ka = (b2 & 0x80000000u) ? ~b2 : (b2 ^ 0x80000000u);
            sh.Kl[i] = ((unsigned long long)(~ka) << 32) | (unsigned int)i;
        }
        __syncthreads();
        int il = t >> 5, sub = t & 31;   // 8 i's per block, 32 threads each
        int i = blk * 8 + il;
        unsigned long long ki = sh.Kl[i];
        int c0 = 0, c1 = 0, c2 = 0, c3 = 0;
        for (int jj = 0; jj < NN; jj += 128) {
            int j = sub + jj;
            c0 += (sh.Kl[j]      < ki) ? 1 : 0;
            c1 += (sh.Kl[j + 32] < ki) ? 1 : 0;
            c2 += (sh.Kl[j + 64] < ki) ? 1 : 0;
            c3 += (sh.Kl[j + 96] < ki) ? 1 : 0;
        }
        int cnt = (c0 + c1) + (c2 + c3);
        for (int off = 16; off > 0; off >>= 1) cnt += __shfl_down(cnt, off, 32);
        if (sub == 0 && cnt < KK) {   // exact bijection: keys are unique
            idx_int[cnt] = i;
            out_idx[cnt] = (float)i;
        }
    }
    grid.sync();

    // ======== P3: rowsums (4 j per block, wave per j) ========
    {
        if (t < NW) sh.Sl[t] = 0ull;
        __syncthreads();
        for (int j = t; j < KK; j += 256) {
            int ii = idx_int[j];
            atomicOr(&sh.Sl[ii >> 6], 1ull << (ii & 63));
        }
        __syncthreads();
        int j = blk * 4 + wv;
        int r = idx_int[j];
        int c = __popcll(T[(size_t)r * NW + l] & sh.Sl[l]);
        for (int off = 32; off > 0; off >>= 1) c += __shfl_down(c, off);
        if (l == 0) inv_rs[j] = 1.0f / (float)c;
    }
    grid.sync();

    // ======== P4: outputs — 4 g_new rows (block-wide) + 4 new_h rows (wave each) ========
    {
        int r0 = blk * 4;
        Tl4[wv][l] = T[(size_t)idx_int[r0 + wv] * NW + l];
        __syncthreads();
        const int4*   idx4 = (const int4*)idx_int;
        const float4* irs4 = (const float4*)inv_rs;
        for (int c4 = t; c4 < KK / 4; c4 += 256) {
            int4 jc = idx4[c4];
            float4 iv = irs4[c4];
            #pragma unroll
            for (int k = 0; k < 4; ++k) {
                float4 o;
                o.x = ((Tl4[k][jc.x >> 6] >> (jc.x & 63)) & 1ull) ? iv.x : 0.0f;
                o.y = ((Tl4[k][jc.y >> 6] >> (jc.y & 63)) & 1ull) ? iv.y : 0.0f;
                o.z = ((Tl4[k][jc.z >> 6] >> (jc.z & 63)) & 1ull) ? iv.z : 0.0f;
                o.w = ((Tl4[k][jc.w >> 6] >> (jc.w & 63)) & 1ull) ? iv.w : 0.0f;
                ((float4*)(out_gnew + (size_t)(r0 + k) * KK))[c4] = o;
            }
        }
        // new_h: one wave per row, lane l owns float4 l, 4-deep ILP
        int r = r0 + wv;
        int* cols = sh.cols4[wv];
        int cnt = build_list(T, idx_int[r], l, cols, 2048);
        if (cnt > 2048) cnt = 2048;
        const float4* hn4 = (const float4*)hn;
        float4 a0 = {0,0,0,0}, a1 = {0,0,0,0}, a2 = {0,0,0,0}, a3 = {0,0,0,0};
        int j = 0;
        for (; j + 3 < cnt; j += 4) {
            int c0 = cols[j], c1 = cols[j+1], c2 = cols[j+2], c3 = cols[j+3];
            float s0 = scores[c0], s1 = scores[c1], s2 = scores[c2], s3 = scores[c3];
            float4 v0 = hn4[(size_t)c0 * 64 + l];
            float4 v1 = hn4[(size_t)c1 * 64 + l];
            float4 v2 = hn4[(size_t)c2 * 64 + l];
            float4 v3 = hn4[(size_t)c3 * 64 + l];
            a0.x = fmaf(s0, v0.x, a0.x); a0.y = fmaf(s0, v0.y, a0.y);
            a0.z = fmaf(s0, v0.z, a0.z); a0.w = fmaf(s0, v0.w, a0.w);
            a1.x = fmaf(s1, v1.x, a1.x); a1.y = fmaf(s1, v1.y, a1.y);
            a1.z = fmaf(s1, v1.z, a1.z); a1.w = fmaf(s1, v1.w, a1.w);
            a2.x = fmaf(s2, v2.x, a2.x); a2.y = fmaf(s2, v2.y, a2.y);
            a2.z = fmaf(s2, v2.z, a2.z); a2.w = fmaf(s2, v2.w, a2.w);
            a3.x = fmaf(s3, v3.x, a3.x); a3.y = fmaf(s3, v3.y, a3.y);
            a3.z = fmaf(s3, v3.z, a3.z); a3.w = fmaf(s3, v3.w, a3.w);
        }
        for (; j < cnt; ++j) {
            int c0 = cols[j];
            float s0 = scores[c0];
            float4 v0 = hn4[(size_t)c0 * 64 + l];
            a0.x = fmaf(s0, v0.x, a0.x); a0.y = fmaf(s0, v0.y, a0.y);
            a0.z = fmaf(s0, v0.z, a0.z); a0.w = fmaf(s0, v0.w, a0.w);
        }
        float4 acc;
        acc.x = (a0.x + a1.x) + (a2.x + a3.x);
        acc.y = (a0.y + a1.y) + (a2.y + a3.y);
        acc.z = (a0.z + a1.z) + (a2.z + a3.z);
        acc.w = (a0.w + a1.w) + (a2.w + a3.w);
        ((float4*)(out_newh + (size_t)r * DD))[l] = acc;
    }
}

extern "C" void kernel_launch(void* const* d_in, const int* in_sizes, int n_in,
                              void* d_out, int out_size, void* d_ws, size_t ws_size,
                              hipStream_t stream) {
    const float* g      = (const float*)d_in[0];
    const float* h      = (const float*)d_in[1];
    const float* gamma  = (const float*)d_in[2];
    const float* beta   = (const float*)d_in[3];
    const float* w_proj = (const float*)d_in[4];
    const float* b_proj = (const float*)d_in[5];
    const float* sigma1 = (const float*)d_in[6];

    char* p = (char*)d_ws;
    auto alloc = [&](size_t bytes) -> void* {
        void* q = (void*)p;
        p += (bytes + 255) & ~(size_t)255;
        return q;
    };
    double* mu      = (double*)alloc(DD * 8);
    double* rstd    = (double*)alloc(DD * 8);
    double* psum    = (double*)alloc(64 * DD * 8);
    double* psq     = (double*)alloc(64 * DD * 8);
    double* zpf     = (double*)alloc(NN * 8);
    double* Z1      = (double*)alloc(NN * 8);
    double* Z3      = (double*)alloc(NN * 8);
    int*    degi    = (int*)alloc(NN * 4);
    float*  scores  = (float*)alloc(NN * 4);
    int*    idx_int = (int*)alloc(KK * 4);
    float*  inv_rs  = (float*)alloc(KK * 4);
    unsigned long long* B = (unsigned long long*)alloc((size_t)NN * NW * 8);
    unsigned long long* T = (unsigned long long*)alloc((size_t)NN * NW * 8);
    float*  hn      = (float*)alloc((size_t)NN * DD * 4);

    float* out_gnew = (float*)d_out;                       // KK*KK
    float* out_newh = out_gnew + (size_t)KK * KK;          // KK*DD
    float* out_idx  = out_newh + (size_t)KK * DD;          // KK

    hipLaunchKernelGGL(k_pre, dim3(64 + NN), dim3(256), 0, stream, h, g, psum, psq, B);

    void* cargs[] = {
        (void*)&h, (void*)&gamma, (void*)&beta, (void*)&w_proj, (void*)&b_proj,
        (void*)&sigma1, (void*)&psum, (void*)&psq, (void*)&B, (void*)&mu, (void*)&rstd,
        (void*)&hn, (void*)&zpf, (void*)&T, (void*)&Z1, (void*)&Z3, (void*)&degi,
        (void*)&scores, (void*)&idx_int, (void*)&inv_rs,
        (void*)&out_gnew, (void*)&out_newh, (void*)&out_idx
    };
    hipLaunchCooperativeKernel((void*)k_coop, dim3(512), dim3(256), cargs, 0, stream);
}

// Round 8
// 181.069 us; speedup vs baseline: 2.2614x; 2.2614x over previous
//
#include <hip/hip_runtime.h>
#include <math.h>

#define NN 4096
#define DD 256
#define KK 2048
#define NW 64   // u64 words per bitmask row

// Build sorted column list for bitmask row r into LDS `cols` (one wave, lane l).
// Returns total bit count. List is ascending.
__device__ __forceinline__ int build_list(const unsigned long long* __restrict__ B, int r,
                                          int l, int* cols, int cap) {
    unsigned long long word = B[(size_t)r * NW + l];
    int pc = __popcll(word);
    int off = pc;
    for (int d = 1; d < 64; d <<= 1) {
        int n = __shfl_up(off, d);
        if (l >= d) off += n;
    }
    int total = __shfl(off, 63);
    int base = off - pc;
    while (word) {
        int b = (int)__ffsll(word) - 1;
        word &= word - 1;
        if (base < cap) cols[base] = l * 64 + b;
        ++base;
    }
    return total;
}

// ---------------- fused: column stats partials (blocks 0..63) + g bitmask (blocks 64..4159) ----
__global__ void k_pre(const float* __restrict__ h, const float* __restrict__ g,
                      double* __restrict__ psum, double* __restrict__ psq,
                      unsigned long long* __restrict__ B) {
    int blk = blockIdx.x;
    int t = threadIdx.x;   // 256
    if (blk < 64) {
        int d = t;
        int r0 = blk * 64;
        double s0=0,s1=0,s2=0,s3=0,q0=0,q1=0,q2=0,q3=0;
        for (int k = 0; k < 64; k += 4) {
            double x0 = (double)h[(size_t)(r0+k+0) * DD + d];
            double x1 = (double)h[(size_t)(r0+k+1) * DD + d];
            double x2 = (double)h[(size_t)(r0+k+2) * DD + d];
            double x3 = (double)h[(size_t)(r0+k+3) * DD + d];
            s0 += x0; q0 += x0*x0;
            s1 += x1; q1 += x1*x1;
            s2 += x2; q2 += x2*x2;
            s3 += x3; q3 += x3*x3;
        }
        psum[blk * DD + d] = (s0+s1)+(s2+s3);
        psq [blk * DD + d] = (q0+q1)+(q2+q3);
    } else {
        int i = blk - 64;
        int q = t >> 6, l = t & 63;
        const float4* g4 = (const float4*)(g + (size_t)i * NN);
        for (int wi = 0; wi < 4; ++wi) {
            float4 v = g4[q * 256 + wi * 64 + l];
            unsigned int nib = (unsigned int)(v.x != 0.f)
                             | ((unsigned int)(v.y != 0.f) << 1)
                             | ((unsigned int)(v.z != 0.f) << 2)
                             | ((unsigned int)(v.w != 0.f) << 3);
            unsigned long long word = (unsigned long long)nib << (4 * (l & 15));
            unsigned int lo = (unsigned int)word, hi = (unsigned int)(word >> 32);
            for (int s = 1; s < 16; s <<= 1) {
                lo |= __shfl_xor(lo, s, 16);
                hi |= __shfl_xor(hi, s, 16);
            }
            if ((l & 15) == 0)
                B[(size_t)i * NW + 16 * q + 4 * wi + (l >> 4)] =
                    ((unsigned long long)hi << 32) | lo;
        }
    }
}

// ---------------- stats final: 1 block x 1024 ----------------
__global__ void k_stats_final(const double* __restrict__ psum, const double* __restrict__ psq,
                              double* __restrict__ mu, double* __restrict__ rstd) {
    __shared__ double rs[4][DD];
    __shared__ double rq[4][DD];
    int t = threadIdx.x;
    int d = t & (DD - 1);
    int q = t >> 8;
    double s0=0,s1=0,q0=0,q1=0;
    int b0 = q * 16;
    for (int k = 0; k < 16; k += 2) {
        s0 += psum[(b0+k)   * DD + d];
        s1 += psum[(b0+k+1) * DD + d];
        q0 += psq [(b0+k)   * DD + d];
        q1 += psq [(b0+k+1) * DD + d];
    }
    rs[q][d] = s0 + s1;
    rq[q][d] = q0 + q1;
    __syncthreads();
    if (q == 0) {
        double S  = (rs[0][d]+rs[1][d]) + (rs[2][d]+rs[3][d]);
        double Q  = (rq[0][d]+rq[1][d]) + (rq[2][d]+rq[3][d]);
        double m  = S / (double)NN;
        double var = Q / (double)NN - m * m;
        mu[d]   = m;
        rstd[d] = 1.0 / sqrt(var + 1e-5);
    }
}

// ---- fused main: blocks 0..1023 = agg+norm+zpf (wave-per-row); 1024..2047 = twohop -----------
__global__ void k_main(const float* __restrict__ h, const double* __restrict__ mu,
                       const double* __restrict__ rstd, const float* __restrict__ gamma,
                       const float* __restrict__ beta, const unsigned long long* __restrict__ Bm,
                       const float* __restrict__ w, const float* __restrict__ bp,
                       float* __restrict__ hn, double* __restrict__ zpf,
                       unsigned long long* __restrict__ T, double* __restrict__ Z1,
                       double* __restrict__ Z3, int* __restrict__ degi) {
    __shared__ int cols[4][136];
    int blk = blockIdx.x;
    int t = threadIdx.x;
    int wv = t >> 6, l = t & 63;
    if (blk < 1024) {
        int r = blk * 4 + wv;
        int cnt = build_list(Bm, r, l, cols[wv], 128);
        if (cnt > 128) cnt = 128;
        const float4* h4 = (const float4*)h;
        double s0=0,s1=0,s2=0,s3=0;
        double u0=0,u1=0,u2=0,u3=0;
        int j = 0;
        for (; j + 3 < cnt; j += 4) {
            float4 v0 = h4[(size_t)cols[wv][j]     * 64 + l];
            float4 v1 = h4[(size_t)cols[wv][j + 1] * 64 + l];
            float4 v2 = h4[(size_t)cols[wv][j + 2] * 64 + l];
            float4 v3 = h4[(size_t)cols[wv][j + 3] * 64 + l];
            s0 += (double)v0.x; s1 += (double)v0.y; s2 += (double)v0.z; s3 += (double)v0.w;
            u0 += (double)v1.x; u1 += (double)v1.y; u2 += (double)v1.z; u3 += (double)v1.w;
            s0 += (double)v2.x; s1 += (double)v2.y; s2 += (double)v2.z; s3 += (double)v2.w;
            u0 += (double)v3.x; u1 += (double)v3.y; u2 += (double)v3.z; u3 += (double)v3.w;
        }
        for (; j < cnt; ++j) {
            float4 v0 = h4[(size_t)cols[wv][j] * 64 + l];
            s0 += (double)v0.x; s1 += (double)v0.y; s2 += (double)v0.z; s3 += (double)v0.w;
        }
        s0 += u0; s1 += u1; s2 += u2; s3 += u3;
        const double2* mu2 = (const double2*)mu;
        const double2* rs2 = (const double2*)rstd;
        const float4*  ga4 = (const float4*)gamma;
        const float4*  be4 = (const float4*)beta;
        const float4*  w4  = (const float4*)w;
        double2 mA = mu2[2*l], mB = mu2[2*l+1];
        double2 rA = rs2[2*l], rB = rs2[2*l+1];
        float4 ga = ga4[l], be = be4[l], wl = w4[l];
        double inv = 1.0 / (double)cnt;
        double g0 = (s0 * inv - mA.x) * rA.x * (double)ga.x + (double)be.x;
        double g1 = (s1 * inv - mA.y) * rA.y * (double)ga.y + (double)be.y;
        double g2 = (s2 * inv - mB.x) * rB.x * (double)ga.z + (double)be.z;
        double g3 = (s3 * inv - mB.y) * rB.y * (double)ga.w + (double)be.w;
        float4 hv = h4[(size_t)r * 64 + l];
        double h0 = ((double)hv.x - mA.x) * rA.x * (double)ga.x + (double)be.x;
        double h1 = ((double)hv.y - mA.y) * rA.y * (double)ga.y + (double)be.y;
        double h2 = ((double)hv.z - mB.x) * rB.x * (double)ga.z + (double)be.z;
        double h3 = ((double)hv.w - mB.y) * rB.y * (double)ga.w + (double)be.w;
        // normalized row (fp32) for the output path
        float4 o = { (float)h0, (float)h1, (float)h2, (float)h3 };
        ((float4*)hn)[(size_t)r * 64 + l] = o;
        double z1p = (fabs(h0 - g0) + fabs(h1 - g1)) + (fabs(h2 - g2) + fabs(h3 - g3));
        double z3p = (g0 * (double)wl.x + g1 * (double)wl.y)
                   + (g2 * (double)wl.z + g3 * (double)wl.w);
        double zfp = (h0 * (double)wl.x + h1 * (double)wl.y)
                   + (h2 * (double)wl.z + h3 * (double)wl.w);
        for (int off = 32; off > 0; off >>= 1) {
            z1p += __shfl_down(z1p, off);
            z3p += __shfl_down(z3p, off);
            zfp += __shfl_down(zfp, off);
        }
        if (l == 0) {
            Z1[r] = z1p;
            Z3[r] = z3p + (double)bp[0];
            zpf[r] = zfp + (double)bp[0];
            degi[r] = cnt;
        }
    } else {
        // ---- twohop, wave per row, 4-deep ILP ----
        int r = (blk - 1024) * 4 + wv;
        int cnt = build_list(Bm, r, l, cols[wv], 128);
        if (cnt > 128) cnt = 128;
        unsigned long long a0 = 0ull, a1 = 0ull, a2 = 0ull, a3 = 0ull;
        int j = 0;
        for (; j + 3 < cnt; j += 4) {
            a0 |= Bm[(size_t)cols[wv][j]     * NW + l];
            a1 |= Bm[(size_t)cols[wv][j + 1] * NW + l];
            a2 |= Bm[(size_t)cols[wv][j + 2] * NW + l];
            a3 |= Bm[(size_t)cols[wv][j + 3] * NW + l];
        }
        for (; j < cnt; ++j) a0 |= Bm[(size_t)cols[wv][j] * NW + l];
        T[(size_t)r * NW + l] = (a0 | a1) | (a2 | a3);
    }
}

// ---------------- scores: each of 16 blocks redundantly reduces softmax stats (deterministic) ----
__global__ void k_scorekeys(const double* __restrict__ Z1, const double* __restrict__ Z3,
                            const double* __restrict__ zpf, const int* __restrict__ degi,
                            const float* __restrict__ sigma1, float* __restrict__ scores,
                            unsigned long long* __restrict__ keys) {
    __shared__ double red[256];
    int t = threadIdx.x;
    double mx = -1e300;
    for (int k = 0; k < 16; ++k) mx = fmax(mx, Z3[t + 256 * k]);
    red[t] = mx;
    __syncthreads();
    for (int s = 128; s > 0; s >>= 1) {
        if (t < s) red[t] = fmax(red[t], red[t + s]);
        __syncthreads();
    }
    double M = red[0];
    __syncthreads();
    double se = 0.0;
    for (int k = 0; k < 16; ++k) se += exp(Z3[t + 256 * k] - M);
    red[t] = se;
    __syncthreads();
    for (int s = 128; s > 0; s >>= 1) {
        if (t < s) red[t] += red[t + s];
        __syncthreads();
    }
    double sum = red[0];
    int i = blockIdx.x * 256 + t;
    double s1 = (double)sigma1[0];
    double pg = exp(Z3[i] - M) / sum;
    double pl = 1.0 / (1.0 + exp(-(Z1[i] + (double)degi[i])));
    double pt = 1.0 / (1.0 + exp(-(pl + pg)));
    double pf = 1.0 / (1.0 + exp(-zpf[i]));
    float sc = (float)(s1 * pt + (1.0 - s1) * pf);
    scores[i] = sc;
    unsigned int b2 = __float_as_uint(sc);
    unsigned int ka = (b2 & 0x80000000u) ? ~b2 : (b2 ^ 0x80000000u);  // ascending order key
    keys[i] = ((unsigned long long)(~ka) << 32) | (unsigned int)i;    // asc = desc score, asc idx
}

// ---------------- rank-by-counting top-k scatter (no atomics) ----------------
__global__ void k_rank(const unsigned long long* __restrict__ keys, int* __restrict__ idx_int,
                       float* __restrict__ out_idx) {
    __shared__ unsigned long long Kl[NN];
    int t = threadIdx.x;
    for (int i = t; i < NN; i += 256) Kl[i] = keys[i];
    __syncthreads();
    int il = t >> 4, sub = t & 15;
    int i = blockIdx.x * 16 + il;
    unsigned long long ki = Kl[i];
    int c0 = 0, c1 = 0, c2 = 0, c3 = 0;
    for (int jj = 0; jj < 256; jj += 4) {
        int j = sub + (jj << 4);
        c0 += (Kl[j]      < ki) ? 1 : 0;
        c1 += (Kl[j + 16] < ki) ? 1 : 0;
        c2 += (Kl[j + 32] < ki) ? 1 : 0;
        c3 += (Kl[j + 48] < ki) ? 1 : 0;
    }
    int cnt = (c0 + c1) + (c2 + c3);
    for (int off = 8; off > 0; off >>= 1) cnt += __shfl_down(cnt, off, 16);
    if (sub == 0 && cnt < KK) {   // exact bijection: keys are unique
        idx_int[cnt] = i;
        out_idx[cnt] = (float)i;
    }
}

// ---------------- row sums: 32 blocks x 64 (single wave — no barriers); S rebuilt in LDS -------
__global__ void k_rowsum(const unsigned long long* __restrict__ T, const int* __restrict__ idx_int,
                         float* __restrict__ inv_rs) {
    __shared__ unsigned long long Sl[NW];
    int t = threadIdx.x;   // 64
    Sl[t] = 0ull;
    for (int j = t; j < KK; j += 64) {
        int ii = idx_int[j];
        atomicOr(&Sl[ii >> 6], 1ull << (ii & 63));
    }
    // single-wave block: LDS ops are program-ordered; no barrier needed
    int j = blockIdx.x * 64 + t;
    int r = idx_int[j];
    const unsigned long long* Tr = T + (size_t)r * NW;
    int c0 = 0, c1 = 0, c2 = 0, c3 = 0;
    for (int w = 0; w < NW; w += 4) {
        c0 += __popcll(Tr[w]     & Sl[w]);
        c1 += __popcll(Tr[w + 1] & Sl[w + 1]);
        c2 += __popcll(Tr[w + 2] & Sl[w + 2]);
        c3 += __popcll(Tr[w + 3] & Sl[w + 3]);
    }
    inv_rs[j] = 1.0f / (float)((c0 + c1) + (c2 + c3));
}

// ---------------- fused outputs: g_new (blocks 0..2047) + new_h (blocks 2048..4095) ----------
__global__ void k_out(const unsigned long long* __restrict__ T, const int* __restrict__ idx_int,
                      const float* __restrict__ inv_rs, const float* __restrict__ scores,
                      const float* __restrict__ hn, float* __restrict__ out_gnew,
                      float* __restrict__ out_newh) {
    __shared__ unsigned long long Tl[NW];
    __shared__ int cols[2048];
    __shared__ int s_cnt;
    __shared__ float4 red[4][64];
    int blk = blockIdx.x;
    int t = threadIdx.x;   // 256
    if (blk < KK) {
        // ---- g_new row ----
        int r = blk;
        if (t < NW) Tl[t] = T[(size_t)idx_int[r] * NW + t];
        __syncthreads();
        const int4*   idx4 = (const int4*)idx_int;
        const float4* irs4 = (const float4*)inv_rs;
        float4* out4 = (float4*)(out_gnew + (size_t)r * KK);
        for (int c4 = t; c4 < KK / 4; c4 += 256) {
            int4 jc = idx4[c4];
            float4 iv = irs4[c4];
            float4 o;
            o.x = ((Tl[jc.x >> 6] >> (jc.x & 63)) & 1ull) ? iv.x : 0.0f;
            o.y = ((Tl[jc.y >> 6] >> (jc.y & 63)) & 1ull) ? iv.y : 0.0f;
            o.z = ((Tl[jc.z >> 6] >> (jc.z & 63)) & 1ull) ? iv.z : 0.0f;
            o.w = ((Tl[jc.w >> 6] >> (jc.w & 63)) & 1ull) ? iv.w : 0.0f;
            out4[c4] = o;
        }
    } else {
        // ---- new_h row: 4-wave float4 gather, 8-deep ILP, fused score scaling ----
        int r = blk - KK;
        int wv = t >> 6, l = t & 63;
        if (t < 64) {
            int total = build_list(T, idx_int[r], t, cols, 2048);
            if (t == 63) s_cnt = total;
        }
        __syncthreads();
        int cnt = s_cnt < 2048 ? s_cnt : 2048;
        const float4* hn4 = (const float4*)hn;
        float4 a0 = {0,0,0,0}, a1 = {0,0,0,0}, a2 = {0,0,0,0}, a3 = {0,0,0,0};
        float4 a4 = {0,0,0,0}, a5 = {0,0,0,0}, a6 = {0,0,0,0}, a7 = {0,0,0,0};
        int j = wv;
        for (; j + 28 < cnt; j += 32) {
            int c0 = cols[j],      c1 = cols[j + 4],  c2 = cols[j + 8],  c3 = cols[j + 12];
            int c4 = cols[j + 16], c5 = cols[j + 20], c6 = cols[j + 24], c7 = cols[j + 28];
            float s0 = scores[c0], s1 = scores[c1], s2 = scores[c2], s3 = scores[c3];
            float s4 = scores[c4], s5 = scores[c5], s6 = scores[c6], s7 = scores[c7];
            float4 v0 = hn4[(size_t)c0 * 64 + l];
            float4 v1 = hn4[(size_t)c1 * 64 + l];
            float4 v2 = hn4[(size_t)c2 * 64 + l];
            float4 v3 = hn4[(size_t)c3 * 64 + l];
            float4 v4 = hn4[(size_t)c4 * 64 + l];
            float4 v5 = hn4[(size_t)c5 * 64 + l];
            float4 v6 = hn4[(size_t)c6 * 64 + l];
            float4 v7 = hn4[(size_t)c7 * 64 + l];
            a0.x = fmaf(s0, v0.x, a0.x); a0.y = fmaf(s0, v0.y, a0.y);
            a0.z = fmaf(s0, v0.z, a0.z); a0.w = fmaf(s0, v0.w, a0.w);
            a1.x = fmaf(s1, v1.x, a1.x); a1.y = fmaf(s1, v1.y, a1.y);
            a1.z = fmaf(s1, v1.z, a1.z); a1.w = fmaf(s1, v1.w, a1.w);
            a2.x = fmaf(s2, v2.x, a2.x); a2.y = fmaf(s2, v2.y, a2.y);
            a2.z = fmaf(s2, v2.z, a2.z); a2.w = fmaf(s2, v2.w, a2.w);
            a3.x = fmaf(s3, v3.x, a3.x); a3.y = fmaf(s3, v3.y, a3.y);
            a3.z = fmaf(s3, v3.z, a3.z); a3.w = fmaf(s3, v3.w, a3.w);
            a4.x = fmaf(s4, v4.x, a4.x); a4.y = fmaf(s4, v4.y, a4.y);
            a4.z = fmaf(s4, v4.z, a4.z); a4.w = fmaf(s4, v4.w, a4.w);
            a5.x = fmaf(s5, v5.x, a5.x); a5.y = fmaf(s5, v5.y, a5.y);
            a5.z = fmaf(s5, v5.z, a5.z); a5.w = fmaf(s5, v5.w, a5.w);
            a6.x = fmaf(s6, v6.x, a6.x); a6.y = fmaf(s6, v6.y, a6.y);
            a6.z = fmaf(s6, v6.z, a6.z); a6.w = fmaf(s6, v6.w, a6.w);
            a7.x = fmaf(s7, v7.x, a7.x); a7.y = fmaf(s7, v7.y, a7.y);
            a7.z = fmaf(s7, v7.z, a7.z); a7.w = fmaf(s7, v7.w, a7.w);
        }
        for (; j < cnt; j += 4) {
            int c0 = cols[j];
            float s0 = scores[c0];
            float4 v0 = hn4[(size_t)c0 * 64 + l];
            a0.x = fmaf(s0, v0.x, a0.x); a0.y = fmaf(s0, v0.y, a0.y);
            a0.z = fmaf(s0, v0.z, a0.z); a0.w = fmaf(s0, v0.w, a0.w);
        }
        float4 acc;
        acc.x = ((a0.x + a1.x) + (a2.x + a3.x)) + ((a4.x + a5.x) + (a6.x + a7.x));
        acc.y = ((a0.y + a1.y) + (a2.y + a3.y)) + ((a4.y + a5.y) + (a6.y + a7.y));
        acc.z = ((a0.z + a1.z) + (a2.z + a3.z)) + ((a4.z + a5.z) + (a6.z + a7.z));
        acc.w = ((a0.w + a1.w) + (a2.w + a3.w)) + ((a4.w + a5.w) + (a6.w + a7.w));
        red[wv][l] = acc;
        __syncthreads();
        if (t < 64) {
            float4 r0 = red[0][t], r1 = red[1][t], r2 = red[2][t], r3 = red[3][t];
            float4 o;
            o.x = (r0.x + r1.x) + (r2.x + r3.x);
            o.y = (r0.y + r1.y) + (r2.y + r3.y);
            o.z = (r0.z + r1.z) + (r2.z + r3.z);
            o.w = (r0.w + r1.w) + (r2.w + r3.w);
            ((float4*)(out_newh + (size_t)r * DD))[t] = o;
        }
    }
}

extern "C" void kernel_launch(void* const* d_in, const int* in_sizes, int n_in,
                              void* d_out, int out_size, void* d_ws, size_t ws_size,
                              hipStream_t stream) {
    const float* g      = (const float*)d_in[0];
    const float* h      = (const float*)d_in[1];
    const float* gamma  = (const float*)d_in[2];
    const float* beta   = (const float*)d_in[3];
    const float* w_proj = (const float*)d_in[4];
    const float* b_proj = (const float*)d_in[5];
    const float* sigma1 = (const float*)d_in[6];

    char* p = (char*)d_ws;
    auto alloc = [&](size_t bytes) -> void* {
        void* q = (void*)p;
        p += (bytes + 255) & ~(size_t)255;
        return q;
    };
    double* mu      = (double*)alloc(DD * 8);
    double* rstd    = (double*)alloc(DD * 8);
    double* psum    = (double*)alloc(64 * DD * 8);
    double* psq     = (double*)alloc(64 * DD * 8);
    double* zpf     = (double*)alloc(NN * 8);
    double* Z1      = (double*)alloc(NN * 8);
    double* Z3      = (double*)alloc(NN * 8);
    int*    degi    = (int*)alloc(NN * 4);
    float*  scores  = (float*)alloc(NN * 4);
    unsigned long long* keys = (unsigned long long*)alloc(NN * 8);
    int*    idx_int = (int*)alloc(KK * 4);
    float*  inv_rs  = (float*)alloc(KK * 4);
    unsigned long long* B = (unsigned long long*)alloc((size_t)NN * NW * 8);
    unsigned long long* T = (unsigned long long*)alloc((size_t)NN * NW * 8);
    float*  hn      = (float*)alloc((size_t)NN * DD * 4);

    float* out_gnew = (float*)d_out;                       // KK*KK
    float* out_newh = out_gnew + (size_t)KK * KK;          // KK*DD
    float* out_idx  = out_newh + (size_t)KK * DD;          // KK

    hipLaunchKernelGGL(k_pre,         dim3(64 + NN), dim3(256),  0, stream, h, g, psum, psq, B);
    hipLaunchKernelGGL(k_stats_final, dim3(1),       dim3(1024), 0, stream, psum, psq, mu, rstd);
    hipLaunchKernelGGL(k_main,        dim3(2048),    dim3(256),  0, stream, h, mu, rstd, gamma, beta, B, w_proj, b_proj, hn, zpf, T, Z1, Z3, degi);
    hipLaunchKernelGGL(k_scorekeys,   dim3(16),      dim3(256),  0, stream, Z1, Z3, zpf, degi, sigma1, scores, keys);
    hipLaunchKernelGGL(k_rank,        dim3(256),     dim3(256),  0, stream, keys, idx_int, out_idx);
    hipLaunchKernelGGL(k_rowsum,      dim3(32),      dim3(64),   0, stream, T, idx_int, inv_rs);
    hipLaunchKernelGGL(k_out,         dim3(2 * KK),  dim3(256),  0, stream, T, idx_int, inv_rs, scores, hn, out_gnew, out_newh);
}